// Round 1
// baseline (348.958 us; speedup 1.0000x reference)
//
#include <hip/hip_runtime.h>
#include <hip/hip_bf16.h>
#include <cstddef>
#include <cstdint>

#define B_ 2
#define D_ 12
#define H_ 200
#define W_ 200
#define HW_ (H_ * W_)
#define DHW_ (D_ * H_ * W_)
#define CELLS_ (B_ * D_ * H_ * W_)   // 960000
#define N_ 60000
#define CIN_ 2
#define COUT_ 64
#define K27 27
#define EPS_ 1e-5f

// ---------------------------------------------------------------------------
// Kernel A: dense cell -> point_id map. scatter[13][n] is the identity tap
// (fz,fy,fx)=(1,1,1) = point n's own cell, always in-bounds. map pre-set to
// -1 via memset(0xFF).
// ---------------------------------------------------------------------------
__global__ void fill_map_kernel(const int* __restrict__ scatter,
                                int* __restrict__ map) {
    int n = blockIdx.x * blockDim.x + threadIdx.x;
    if (n >= N_) return;
    map[scatter[13 * N_ + n]] = n;
}

// ---------------------------------------------------------------------------
// Kernel B: fused stencil-gather conv + LayerNorm + ReLU.
// 16 lanes per cell, float4 (4 channels) per lane, 4 cells per wave.
//
// Round-N change vs previous version: FEATURE FORWARDING. The probing lane
// that finds a hit loads the point's float2 feature immediately, so all tap
// feature loads issue in parallel during the probe phase. The hit loop then
// broadcasts the 2 feature floats via shfl (LDS-speed) instead of doing a
// dependent scattered global load per hit — removing ~200-400 cy of L2
// latency from the per-hit serial chain.
// ---------------------------------------------------------------------------
__global__ __launch_bounds__(256) void gather_cell16_kernel(
        const float* __restrict__ feat,
        const float* __restrict__ weight,
        const float* __restrict__ gamma,
        const float* __restrict__ beta,
        const int* __restrict__ map,
        float* __restrict__ out) {
    const int tid = threadIdx.x;
    const int slot = tid >> 4;              // cell slot within block, 0..15
    const int q    = tid & 15;              // lane within 16-lane group
    const int gw   = slot & 3;              // group within wave, 0..3

    const int x  = blockIdx.x * 16 + slot;  // cell x
    const int y  = blockIdx.y;              // cell y
    const int bz = blockIdx.z;              // b*D + z  (0..23)
    const int b  = bz >= D_ ? 1 : 0;        // B_=2
    const int z  = bz - b * D_;

    const bool cell_ok = (x < W_);

    // hoist gamma/beta loads: overlap their latency with the probe phase
    float4 gm = *reinterpret_cast<const float4*>(&gamma[q * 4]);
    float4 bt = *reinterpret_cast<const float4*>(&beta[q * 4]);

    // ---- probe round 1: taps 0..15 (lane q probes tap q) ----
    int n1 = -1;
    {
        int fz = q / 9;
        int t  = q - fz * 9;
        int fy = t / 3;
        int fx = t - fy * 3;
        int pz = z + fz - 1, py = y + fy - 1, px = x + fx - 1;
        if (cell_ok && pz >= 0 && pz < D_ && py >= 0 && py < H_ &&
            px >= 0 && px < W_)
            n1 = map[((b * D_ + pz) * H_ + py) * W_ + px];
    }
    // ---- probe round 2: taps 16..26 (lanes 0..10 of each group) ----
    int n2 = -1;
    if (q < K27 - 16) {
        int tap = q + 16;
        int fz = tap / 9;
        int t  = tap - fz * 9;
        int fy = t / 3;
        int fx = t - fy * 3;
        int pz = z + fz - 1, py = y + fy - 1, px = x + fx - 1;
        if (cell_ok && pz >= 0 && pz < D_ && py >= 0 && py < H_ &&
            px >= 0 && px < W_)
            n2 = map[((b * D_ + pz) * H_ + py) * W_ + px];
    }

    // ---- feature forwarding: each probing lane fetches its point's feature
    // now, so the loads for all hit taps are in flight concurrently ----
    float2 f1 = {0.f, 0.f}, f2 = {0.f, 0.f};
    if (n1 >= 0) f1 = *reinterpret_cast<const float2*>(&feat[n1 * CIN_]);
    if (n2 >= 0) f2 = *reinterpret_cast<const float2*>(&feat[n2 * CIN_]);

    unsigned long long ball1 = __ballot(n1 >= 0);
    unsigned long long ball2 = __ballot(n2 >= 0);
    const int shift = gw * 16;
    unsigned int mask = (unsigned int)((ball1 >> shift) & 0xFFFFull)
                      | ((unsigned int)((ball2 >> shift) & 0x7FFull) << 16);
    const bool active = (mask != 0u);

    // ---- gather-conv over actual hits: shfl the 2 feature floats (fast),
    // weight loads are L1-resident (13.8 KB total) ----
    float4 acc = {0.f, 0.f, 0.f, 0.f};
    while (mask) {
        int l = __ffs(mask) - 1;            // tap index == weight k
        mask &= mask - 1;
        int src = (gw << 4) + (l & 15);     // source lane in same group
        float fx = __shfl((l < 16) ? f1.x : f2.x, src, 64);
        float fy = __shfl((l < 16) ? f1.y : f2.y, src, 64);
        const float* wk = &weight[l * (CIN_ * COUT_) + q * 4];
        float4 w0 = *reinterpret_cast<const float4*>(wk);
        float4 w1 = *reinterpret_cast<const float4*>(wk + COUT_);
        acc.x += fx * w0.x + fy * w1.x;
        acc.y += fx * w0.y + fy * w1.y;
        acc.z += fx * w0.z + fy * w1.z;
        acc.w += fx * w0.w + fy * w1.w;
    }

    // ---- LayerNorm over 64 channels: butterfly across the 16-lane group ----
    float s  = acc.x + acc.y + acc.z + acc.w;
    float s2 = acc.x * acc.x + acc.y * acc.y + acc.z * acc.z + acc.w * acc.w;
    #pragma unroll
    for (int m = 1; m < 16; m <<= 1) {
        s  += __shfl_xor(s,  m, 16);
        s2 += __shfl_xor(s2, m, 16);
    }
    float mu  = s * (1.0f / COUT_);
    float var = s2 * (1.0f / COUT_) - mu * mu;
    float inv = rsqrtf(var + EPS_);

    float4 r;
    if (active) {
        r.x = fmaxf((acc.x - mu) * inv * gm.x + bt.x, 0.0f);
        r.y = fmaxf((acc.y - mu) * inv * gm.y + bt.y, 0.0f);
        r.z = fmaxf((acc.z - mu) * inv * gm.z + bt.z, 0.0f);
        r.w = fmaxf((acc.w - mu) * inv * gm.w + bt.w, 0.0f);
    } else {
        r.x = r.y = r.z = r.w = 0.0f;       // inactive -> exact zeros
    }

    if (cell_ok) {
        size_t obase = ((size_t)((bz * H_ + y) * W_ + x)) * COUT_ + q * 4;
        *reinterpret_cast<float4*>(&out[obase]) = r;
    }
}

extern "C" void kernel_launch(void* const* d_in, const int* in_sizes, int n_in,
                              void* d_out, int out_size, void* d_ws, size_t ws_size,
                              hipStream_t stream) {
    const float* feat    = (const float*)d_in[0];   // (N, 2)
    const float* weight  = (const float*)d_in[1];   // (27, 2, 64)
    const float* gamma   = (const float*)d_in[2];   // (64,)
    const float* beta    = (const float*)d_in[3];   // (64,)
    const int*   scatter = (const int*)d_in[4];     // (27, N)
    float* out = (float*)d_out;                     // (CELLS, 64)

    int* map = (int*)d_ws;                          // CELLS * 4 B = 3.84 MB

    hipMemsetAsync(map, 0xFF, (size_t)CELLS_ * sizeof(int), stream);
    {
        int block = 256;
        int grid = (N_ + block - 1) / block;
        fill_map_kernel<<<grid, block, 0, stream>>>(scatter, map);
    }

    // fused gather-conv + LN + ReLU: 16 cells per 256-thread block
    {
        dim3 block(256, 1, 1);
        dim3 grid((W_ + 15) / 16, H_, B_ * D_);     // 13 x 200 x 24
        gather_cell16_kernel<<<grid, block, 0, stream>>>(feat, weight, gamma,
                                                         beta, map, out);
    }
}

// Round 3
// 309.974 us; speedup vs baseline: 1.1258x; 1.1258x over previous
//
#include <hip/hip_runtime.h>
#include <hip/hip_bf16.h>
#include <cstddef>
#include <cstdint>

#define B_ 2
#define D_ 12
#define H_ 200
#define W_ 200
#define HW_ (H_ * W_)
#define DHW_ (D_ * H_ * W_)
#define CELLS_ (B_ * D_ * H_ * W_)   // 960000
#define N_ 60000
#define CIN_ 2
#define COUT_ 64
#define K27 27
#define EPS_ 1e-5f

typedef float f32x4 __attribute__((ext_vector_type(4)));

// ---------------------------------------------------------------------------
// Kernel A: dense cell -> point_id map. scatter[13][n] is the identity tap
// (fz,fy,fx)=(1,1,1) = point n's own cell, always in-bounds. map pre-set to
// -1 via memset(0xFF).
// ---------------------------------------------------------------------------
__global__ void fill_map_kernel(const int* __restrict__ scatter,
                                int* __restrict__ map) {
    int n = blockIdx.x * blockDim.x + threadIdx.x;
    if (n >= N_) return;
    map[scatter[13 * N_ + n]] = n;
}

// ---------------------------------------------------------------------------
// DPP 16-lane allreduce-add: row_mirror, row_half_mirror, quad_perm xor2,
// quad_perm xor1. Four VALU-speed adds (~3cy each) replace four serial
// ds_swizzle shuffles (~60cy each). ctrl must be a compile-time constant ->
// template parameter. Orbit closure: {i,15-i} -> add h-mirror -> merge i^2
// -> merge i^1 covers all 16 lanes of the row.
// ---------------------------------------------------------------------------
template <int CTRL>
__device__ __forceinline__ float dpp_add(float v) {
    int t = __builtin_amdgcn_update_dpp(
        0, __float_as_int(v), CTRL, 0xF, 0xF, true);
    return v + __int_as_float(t);
}
__device__ __forceinline__ float row16_allreduce_add(float v) {
    v = dpp_add<0x140>(v);  // row_mirror       i <-> 15-i
    v = dpp_add<0x141>(v);  // row_half_mirror  i <-> (i&8)|(7-(i&7))
    v = dpp_add<0x4E>(v);   // quad_perm(2,3,0,1)  i <-> i^2
    v = dpp_add<0xB1>(v);   // quad_perm(1,0,3,2)  i <-> i^1
    return v;
}

// ---------------------------------------------------------------------------
// Kernel B: fused stencil-gather conv + LayerNorm + ReLU.
// 16 lanes per cell, float4 (4 channels) per lane, 4 cells per wave.
// Round-3 changes (round-2 intent, compile-fixed):
//   - LN reduction via DPP row allreduce (VALU pipe) instead of 8 serial
//     ds_swizzle shuffles (~450 cy serial LDS latency removed per wave)
//   - nontemporal output stores (native ext_vector f32x4): the 245.8 MB
//     write stream no longer evicts map/feat from each XCD's 4 MiB L2
// ---------------------------------------------------------------------------
__global__ __launch_bounds__(256) void gather_cell16_kernel(
        const float* __restrict__ feat,
        const float* __restrict__ weight,
        const float* __restrict__ gamma,
        const float* __restrict__ beta,
        const int* __restrict__ map,
        float* __restrict__ out) {
    const int tid = threadIdx.x;
    const int slot = tid >> 4;              // cell slot within block, 0..15
    const int q    = tid & 15;              // lane within 16-lane group
    const int gw   = slot & 3;              // group within wave, 0..3

    const int x  = blockIdx.x * 16 + slot;  // cell x
    const int y  = blockIdx.y;              // cell y
    const int bz = blockIdx.z;              // b*D + z  (0..23)
    const int b  = bz >= D_ ? 1 : 0;        // B_=2
    const int z  = bz - b * D_;

    const bool cell_ok = (x < W_);

    // hoist gamma/beta loads: overlap their latency with the probe phase
    float4 gm = *reinterpret_cast<const float4*>(&gamma[q * 4]);
    float4 bt = *reinterpret_cast<const float4*>(&beta[q * 4]);

    // ---- probe round 1: taps 0..15 (lane q probes tap q) ----
    int n1 = -1;
    {
        int fz = q / 9;
        int t  = q - fz * 9;
        int fy = t / 3;
        int fx = t - fy * 3;
        int pz = z + fz - 1, py = y + fy - 1, px = x + fx - 1;
        if (cell_ok && pz >= 0 && pz < D_ && py >= 0 && py < H_ &&
            px >= 0 && px < W_)
            n1 = map[((b * D_ + pz) * H_ + py) * W_ + px];
    }
    // ---- probe round 2: taps 16..26 (lanes 0..10 of each group) ----
    int n2 = -1;
    if (q < K27 - 16) {
        int tap = q + 16;
        int fz = tap / 9;
        int t  = tap - fz * 9;
        int fy = t / 3;
        int fx = t - fy * 3;
        int pz = z + fz - 1, py = y + fy - 1, px = x + fx - 1;
        if (cell_ok && pz >= 0 && pz < D_ && py >= 0 && py < H_ &&
            px >= 0 && px < W_)
            n2 = map[((b * D_ + pz) * H_ + py) * W_ + px];
    }

    // ---- feature forwarding: each probing lane fetches its point's feature
    // now, so the loads for all hit taps are in flight concurrently ----
    float2 f1 = {0.f, 0.f}, f2 = {0.f, 0.f};
    if (n1 >= 0) f1 = *reinterpret_cast<const float2*>(&feat[n1 * CIN_]);
    if (n2 >= 0) f2 = *reinterpret_cast<const float2*>(&feat[n2 * CIN_]);

    unsigned long long ball1 = __ballot(n1 >= 0);
    unsigned long long ball2 = __ballot(n2 >= 0);
    const int shift = gw * 16;
    unsigned int mask = (unsigned int)((ball1 >> shift) & 0xFFFFull)
                      | ((unsigned int)((ball2 >> shift) & 0x7FFull) << 16);
    const bool active = (mask != 0u);

    // ---- gather-conv over actual hits: shfl the 2 feature floats (fast),
    // weight loads are L1-resident (13.8 KB total) ----
    float4 acc = {0.f, 0.f, 0.f, 0.f};
    while (mask) {
        int l = __ffs(mask) - 1;            // tap index == weight k
        mask &= mask - 1;
        int src = (gw << 4) + (l & 15);     // source lane in same group
        float fx = __shfl((l < 16) ? f1.x : f2.x, src, 64);
        float fy = __shfl((l < 16) ? f1.y : f2.y, src, 64);
        const float* wk = &weight[l * (CIN_ * COUT_) + q * 4];
        float4 w0 = *reinterpret_cast<const float4*>(wk);
        float4 w1 = *reinterpret_cast<const float4*>(wk + COUT_);
        acc.x += fx * w0.x + fy * w1.x;
        acc.y += fx * w0.y + fy * w1.y;
        acc.z += fx * w0.z + fy * w1.z;
        acc.w += fx * w0.w + fy * w1.w;
    }

    // ---- LayerNorm over 64 channels: DPP allreduce across the 16-lane
    // group (VALU pipe, ~12cy serial vs ~450cy for ds_swizzle butterfly) ----
    float s  = acc.x + acc.y + acc.z + acc.w;
    float s2 = acc.x * acc.x + acc.y * acc.y + acc.z * acc.z + acc.w * acc.w;
    s  = row16_allreduce_add(s);
    s2 = row16_allreduce_add(s2);
    float mu  = s * (1.0f / COUT_);
    float var = s2 * (1.0f / COUT_) - mu * mu;
    float inv = rsqrtf(var + EPS_);

    f32x4 r;
    if (active) {
        r.x = fmaxf((acc.x - mu) * inv * gm.x + bt.x, 0.0f);
        r.y = fmaxf((acc.y - mu) * inv * gm.y + bt.y, 0.0f);
        r.z = fmaxf((acc.z - mu) * inv * gm.z + bt.z, 0.0f);
        r.w = fmaxf((acc.w - mu) * inv * gm.w + bt.w, 0.0f);
    } else {
        r.x = r.y = r.z = r.w = 0.0f;       // inactive -> exact zeros
    }

    if (cell_ok) {
        size_t obase = ((size_t)((bz * H_ + y) * W_ + x)) * COUT_ + q * 4;
        // nontemporal: output is write-once, never re-read; keep it out of L2
        __builtin_nontemporal_store(
            r, reinterpret_cast<f32x4*>(&out[obase]));
    }
}

extern "C" void kernel_launch(void* const* d_in, const int* in_sizes, int n_in,
                              void* d_out, int out_size, void* d_ws, size_t ws_size,
                              hipStream_t stream) {
    const float* feat    = (const float*)d_in[0];   // (N, 2)
    const float* weight  = (const float*)d_in[1];   // (27, 2, 64)
    const float* gamma   = (const float*)d_in[2];   // (64,)
    const float* beta    = (const float*)d_in[3];   // (64,)
    const int*   scatter = (const int*)d_in[4];     // (27, N)
    float* out = (float*)d_out;                     // (CELLS, 64)

    int* map = (int*)d_ws;                          // CELLS * 4 B = 3.84 MB

    (void)hipMemsetAsync(map, 0xFF, (size_t)CELLS_ * sizeof(int), stream);
    {
        int block = 256;
        int grid = (N_ + block - 1) / block;
        fill_map_kernel<<<grid, block, 0, stream>>>(scatter, map);
    }

    // fused gather-conv + LN + ReLU: 16 cells per 256-thread block
    {
        dim3 block(256, 1, 1);
        dim3 grid((W_ + 15) / 16, H_, B_ * D_);     // 13 x 200 x 24
        gather_cell16_kernel<<<grid, block, 0, stream>>>(feat, weight, gamma,
                                                         beta, map, out);
    }
}

// Round 4
// 302.907 us; speedup vs baseline: 1.1520x; 1.0233x over previous
//
#include <hip/hip_runtime.h>
#include <hip/hip_bf16.h>
#include <cstddef>
#include <cstdint>

#define B_ 2
#define D_ 12
#define H_ 200
#define W_ 200
#define HW_ (H_ * W_)
#define DHW_ (D_ * H_ * W_)
#define CELLS_ (B_ * D_ * H_ * W_)   // 960000
#define N_ 60000
#define CIN_ 2
#define COUT_ 64
#define K27 27
#define EPS_ 1e-5f
#define ZCHUNK 6                      // z-planes per workgroup (12 % 6 == 0)

typedef float f32x4 __attribute__((ext_vector_type(4)));

// ---------------------------------------------------------------------------
// Kernel A: dense cell -> point_id map. scatter[13][n] is the identity tap
// (fz,fy,fx)=(1,1,1) = point n's own cell, always in-bounds. map pre-set to
// -1 via memset(0xFF).
// ---------------------------------------------------------------------------
__global__ void fill_map_kernel(const int* __restrict__ scatter,
                                int* __restrict__ map) {
    int n = blockIdx.x * blockDim.x + threadIdx.x;
    if (n >= N_) return;
    map[scatter[13 * N_ + n]] = n;
}

// ---------------------------------------------------------------------------
// DPP 16-lane allreduce-add (VALU pipe, no LDS). ctrl is a template const.
// ---------------------------------------------------------------------------
template <int CTRL>
__device__ __forceinline__ float dpp_add(float v) {
    int t = __builtin_amdgcn_update_dpp(
        0, __float_as_int(v), CTRL, 0xF, 0xF, true);
    return v + __int_as_float(t);
}
__device__ __forceinline__ float row16_allreduce_add(float v) {
    v = dpp_add<0x140>(v);  // row_mirror       i <-> 15-i
    v = dpp_add<0x141>(v);  // row_half_mirror
    v = dpp_add<0x4E>(v);   // quad_perm i <-> i^2
    v = dpp_add<0xB1>(v);   // quad_perm i <-> i^1
    return v;
}

// ---------------------------------------------------------------------------
// Kernel B: fused stencil-gather conv + LayerNorm + ReLU.
// 16 lanes per cell, float4 (4 channels) per lane, 4 cells per wave.
// Round-4 change: GRID-STRIDE OVER Z. 62,400 one-shot WGs -> 10,400 WGs
// each looping over ZCHUNK=6 z-planes. Tests the theory that the ~150 us
// kernel time is dominated by workgroup dispatch/teardown (per-WG fixed
// cost), which would explain why all three intra-kernel latency cuts and a
// 21% HBM slowdown were all neutral. Side benefit: probes of plane z+1 are
// L1-warm from iteration z.
// ---------------------------------------------------------------------------
__global__ __launch_bounds__(256) void gather_cell16_kernel(
        const float* __restrict__ feat,
        const float* __restrict__ weight,
        const float* __restrict__ gamma,
        const float* __restrict__ beta,
        const int* __restrict__ map,
        float* __restrict__ out) {
    const int tid = threadIdx.x;
    const int slot = tid >> 4;              // cell slot within block, 0..15
    const int q    = tid & 15;              // lane within 16-lane group
    const int gw   = slot & 3;              // group within wave, 0..3

    const int x  = blockIdx.x * 16 + slot;  // cell x
    const int y  = blockIdx.y;              // cell y
    const int zi = blockIdx.z;              // z-chunk index, 0..3
    const int bz0 = zi * ZCHUNK;            // first bz of this chunk
    const int b  = bz0 >= D_ ? 1 : 0;       // chunk never straddles b
    const int z0 = bz0 - b * D_;

    const bool cell_ok = (x < W_);

    // tap decomposition for this lane's two probe taps (loop-invariant)
    const int fz1 = q / 9,  t1 = q - fz1 * 9;
    const int fy1 = t1 / 3, fx1 = t1 - fy1 * 3;
    const int tap2 = q + 16;
    const int fz2 = tap2 / 9,  t2 = tap2 - fz2 * 9;
    const int fy2 = t2 / 3,    fx2 = t2 - fy2 * 3;
    const bool has2 = (q < K27 - 16);

    // loop-invariant probe coords in x,y
    const int py1 = y + fy1 - 1, px1 = x + fx1 - 1;
    const int py2 = y + fy2 - 1, px2 = x + fx2 - 1;
    const bool xy1 = cell_ok && py1 >= 0 && py1 < H_ && px1 >= 0 && px1 < W_;
    const bool xy2 = has2 && cell_ok && py2 >= 0 && py2 < H_ &&
                     px2 >= 0 && px2 < W_;

    // hoisted: gamma/beta (loop-invariant)
    float4 gm = *reinterpret_cast<const float4*>(&gamma[q * 4]);
    float4 bt = *reinterpret_cast<const float4*>(&beta[q * 4]);

    for (int j = 0; j < ZCHUNK; ++j) {
        const int z  = z0 + j;
        const int bz = bz0 + j;

        // ---- probe round 1: taps 0..15 ----
        int n1 = -1;
        {
            int pz = z + fz1 - 1;
            if (xy1 && pz >= 0 && pz < D_)
                n1 = map[((b * D_ + pz) * H_ + py1) * W_ + px1];
        }
        // ---- probe round 2: taps 16..26 ----
        int n2 = -1;
        {
            int pz = z + fz2 - 1;
            if (xy2 && pz >= 0 && pz < D_)
                n2 = map[((b * D_ + pz) * H_ + py2) * W_ + px2];
        }

        // ---- feature forwarding: loads for all hit taps in flight now ----
        float2 f1 = {0.f, 0.f}, f2 = {0.f, 0.f};
        if (n1 >= 0) f1 = *reinterpret_cast<const float2*>(&feat[n1 * CIN_]);
        if (n2 >= 0) f2 = *reinterpret_cast<const float2*>(&feat[n2 * CIN_]);

        unsigned long long ball1 = __ballot(n1 >= 0);
        unsigned long long ball2 = __ballot(n2 >= 0);
        const int shift = gw * 16;
        unsigned int mask = (unsigned int)((ball1 >> shift) & 0xFFFFull)
                          | ((unsigned int)((ball2 >> shift) & 0x7FFull) << 16);
        const bool active = (mask != 0u);

        // ---- gather-conv over actual hits ----
        float4 acc = {0.f, 0.f, 0.f, 0.f};
        while (mask) {
            int l = __ffs(mask) - 1;        // tap index == weight k
            mask &= mask - 1;
            int src = (gw << 4) + (l & 15);
            float fx = __shfl((l < 16) ? f1.x : f2.x, src, 64);
            float fy = __shfl((l < 16) ? f1.y : f2.y, src, 64);
            const float* wk = &weight[l * (CIN_ * COUT_) + q * 4];
            float4 w0 = *reinterpret_cast<const float4*>(wk);
            float4 w1 = *reinterpret_cast<const float4*>(wk + COUT_);
            acc.x += fx * w0.x + fy * w1.x;
            acc.y += fx * w0.y + fy * w1.y;
            acc.z += fx * w0.z + fy * w1.z;
            acc.w += fx * w0.w + fy * w1.w;
        }

        // ---- LayerNorm via DPP allreduce (all 64 lanes active here) ----
        float s  = acc.x + acc.y + acc.z + acc.w;
        float s2 = acc.x * acc.x + acc.y * acc.y + acc.z * acc.z
                 + acc.w * acc.w;
        s  = row16_allreduce_add(s);
        s2 = row16_allreduce_add(s2);
        float mu  = s * (1.0f / COUT_);
        float var = s2 * (1.0f / COUT_) - mu * mu;
        float inv = rsqrtf(var + EPS_);

        f32x4 r;
        if (active) {
            r.x = fmaxf((acc.x - mu) * inv * gm.x + bt.x, 0.0f);
            r.y = fmaxf((acc.y - mu) * inv * gm.y + bt.y, 0.0f);
            r.z = fmaxf((acc.z - mu) * inv * gm.z + bt.z, 0.0f);
            r.w = fmaxf((acc.w - mu) * inv * gm.w + bt.w, 0.0f);
        } else {
            r.x = r.y = r.z = r.w = 0.0f;   // inactive -> exact zeros
        }

        if (cell_ok) {
            size_t obase = ((size_t)((bz * H_ + y) * W_ + x)) * COUT_ + q * 4;
            __builtin_nontemporal_store(
                r, reinterpret_cast<f32x4*>(&out[obase]));
        }
    }
}

extern "C" void kernel_launch(void* const* d_in, const int* in_sizes, int n_in,
                              void* d_out, int out_size, void* d_ws, size_t ws_size,
                              hipStream_t stream) {
    const float* feat    = (const float*)d_in[0];   // (N, 2)
    const float* weight  = (const float*)d_in[1];   // (27, 2, 64)
    const float* gamma   = (const float*)d_in[2];   // (64,)
    const float* beta    = (const float*)d_in[3];   // (64,)
    const int*   scatter = (const int*)d_in[4];     // (27, N)
    float* out = (float*)d_out;                     // (CELLS, 64)

    int* map = (int*)d_ws;                          // CELLS * 4 B = 3.84 MB

    (void)hipMemsetAsync(map, 0xFF, (size_t)CELLS_ * sizeof(int), stream);
    {
        int block = 256;
        int grid = (N_ + block - 1) / block;
        fill_map_kernel<<<grid, block, 0, stream>>>(scatter, map);
    }

    // fused gather-conv + LN + ReLU: 16 cells x ZCHUNK z-planes per block
    {
        dim3 block(256, 1, 1);
        dim3 grid((W_ + 15) / 16, H_, (B_ * D_) / ZCHUNK);  // 13 x 200 x 4
        gather_cell16_kernel<<<grid, block, 0, stream>>>(feat, weight, gamma,
                                                         beta, map, out);
    }
}